// Round 1
// baseline (245.296 us; speedup 1.0000x reference)
//
#include <hip/hip_runtime.h>
#include <math.h>

#define NLV 16
#define TBL (1u << 19)
#define HMASK (TBL - 1u)
#define PRIME1 2654435761u

struct Scales { float s[NLV]; };

__global__ __launch_bounds__(256, 4) void hashgrid_mlp_kernel(
    const float2* __restrict__ pts,
    const float2* __restrict__ table,   // [16][524288] float2
    const float*  __restrict__ W1,      // [64][32]
    const float*  __restrict__ W2,      // [3][64]
    float* __restrict__ out,            // [N][3]
    int N, Scales sc)
{
    int i = blockIdx.x * 256 + threadIdx.x;
    if (i >= N) return;

    float2 p = pts[i];
    float enc[32];

#pragma unroll
    for (int l = 0; l < NLV; ++l) {
        float s  = sc.s[l];
        float px = p.x * s;              // f32 mul, bitwise == reference
        float py = p.y * s;
        float fpx = floorf(px), fpy = floorf(py);
        float fx = px - fpx,    fy = py - fpy;
        unsigned bx = (unsigned)(int)fpx;
        unsigned by = (unsigned)(int)fpy;
        unsigned hy0 = by * PRIME1;
        unsigned hy1 = hy0 + PRIME1;     // (by+1)*PRIME1 mod 2^32
        unsigned i00 = ( bx        ^ hy0) & HMASK;
        unsigned i01 = ( bx        ^ hy1) & HMASK;
        unsigned i10 = ((bx + 1u)  ^ hy0) & HMASK;
        unsigned i11 = ((bx + 1u)  ^ hy1) & HMASK;
        const float2* tl = table + (size_t)l * TBL;
        float2 f00 = tl[i00];
        float2 f01 = tl[i01];
        float2 f10 = tl[i10];
        float2 f11 = tl[i11];
        float gx = 1.f - fx, gy = 1.f - fy;
        float w00 = gx * gy, w01 = gx * fy, w10 = fx * gy, w11 = fx * fy;
        enc[2*l]   = w00*f00.x + w01*f01.x + w10*f10.x + w11*f11.x;
        enc[2*l+1] = w00*f00.y + w01*f01.y + w10*f10.y + w11*f11.y;
    }

    float o0 = 0.f, o1 = 0.f, o2 = 0.f;
#pragma unroll
    for (int j = 0; j < 64; ++j) {
        float h = 0.f;
#pragma unroll
        for (int k = 0; k < 32; ++k)
            h = fmaf(enc[k], W1[j*32 + k], h);   // W1 addr uniform -> s_load
        h = fmaxf(h, 0.f);
        o0 = fmaf(h, W2[      j], o0);
        o1 = fmaf(h, W2[ 64 + j], o1);
        o2 = fmaf(h, W2[128 + j], o2);
    }
    out[3*i + 0] = o0;
    out[3*i + 1] = o1;
    out[3*i + 2] = o2;
}

extern "C" void kernel_launch(void* const* d_in, const int* in_sizes, int n_in,
                              void* d_out, int out_size, void* d_ws, size_t ws_size,
                              hipStream_t stream) {
    const float2* pts   = (const float2*)d_in[0];
    const float2* table = (const float2*)d_in[1];
    const float*  W1    = (const float*)d_in[2];
    const float*  W2    = (const float*)d_in[3];
    float* out = (float*)d_out;
    int N = in_sizes[0] / 2;

    // Replicate numpy: np.floor(16 * 1.447269237440378 ** arange(16)).astype(f32)
    // Host pow == glibc pow == numpy's npy_pow -> bit-identical scales
    // (level 15 is a floor boundary: comes out 4095, NOT 4096).
    Scales sc;
    for (int l = 0; l < NLV; ++l)
        sc.s[l] = (float)floor(16.0 * pow(1.447269237440378, (double)l));

    int blocks = (N + 255) / 256;
    hipLaunchKernelGGL(hashgrid_mlp_kernel, dim3(blocks), dim3(256), 0, stream,
                       pts, table, W1, W2, out, N, sc);
}